// Round 1
// baseline (3331.345 us; speedup 1.0000x reference)
//
#include <hip/hip_runtime.h>
#include <math.h>

// ---------------- problem constants ----------------
#define BATCH 32768
#define HID   512
#define NOBJ  5
#define TM    16            // batch rows per block

// O_IDS[5][12]: 10 unordered 'close' pairs then 20 ordered 'above' perms,
// precomputed on host from itertools.combinations/permutations order.
__device__ __constant__ int d_OIDS[5][12] = {
  {0,1,2,3, 10,11,12,13,14,18,22,26},
  {0,4,5,6, 10,14,15,16,17,19,23,27},
  {1,4,7,8, 11,15,18,19,20,21,24,28},
  {2,5,7,9, 12,16,20,22,23,24,25,29},
  {3,6,8,9, 13,17,21,25,26,27,28,29}
};

// ---------------- workspace layout (floats): transposed weights [K][512] etc ----------------
#define OFF_EW0T 0
#define SZ_EW0T  (44*512)
#define OFF_EW1T (OFF_EW0T+SZ_EW0T)
#define SZ_EW1T  (512*512)
#define OFF_WMT  (OFF_EW1T+SZ_EW1T)
#define SZ_WMT   (512*9)
#define OFF_WVT  (OFF_WMT+SZ_WMT)
#define SZ_WVT   (512*9)
#define OFF_DW0T (OFF_WVT+SZ_WVT)
#define SZ_DW0T  (41*512)
#define OFF_DW1T (OFF_DW0T+SZ_DW0T)
#define SZ_DW1T  (512*512)
#define OFF_DW2T (OFF_DW1T+SZ_DW1T)
#define SZ_DW2T  (512*12)
#define WS_FLOATS (OFF_DW2T+SZ_DW2T)   // 583168 floats = 2.33 MB

// ---------------- output layout (floats) ----------------
#define OUT_MEANS (BATCH*30)
#define OUT_LV    (OUT_MEANS + NOBJ*BATCH*9)
#define OUT_Z     (OUT_LV    + NOBJ*BATCH*9)

// ---------------- prep: transpose weights into ws ----------------
__global__ void __launch_bounds__(256)
prep_kernel(const float* __restrict__ eW0, const float* __restrict__ eW1,
            const float* __restrict__ Wm,  const float* __restrict__ Wv,
            const float* __restrict__ dW0, const float* __restrict__ dW1,
            const float* __restrict__ dW2, float* __restrict__ ws)
{
  for (int i = blockIdx.x*blockDim.x + threadIdx.x; i < WS_FLOATS; i += gridDim.x*blockDim.x) {
    float v; int j;
    if      (i < OFF_EW1T) { j = i-OFF_EW0T; v = eW0[(j%512)*44  + (j/512)]; }
    else if (i < OFF_WMT)  { j = i-OFF_EW1T; v = eW1[(j%512)*512 + (j/512)]; }
    else if (i < OFF_WVT)  { j = i-OFF_WMT;  v = Wm [(j%9)*512   + (j/9)];   }
    else if (i < OFF_DW0T) { j = i-OFF_WVT;  v = Wv [(j%9)*512   + (j/9)];   }
    else if (i < OFF_DW1T) { j = i-OFF_DW0T; v = dW0[(j%512)*41  + (j/512)]; }
    else if (i < OFF_DW2T) { j = i-OFF_DW1T; v = dW1[(j%512)*512 + (j/512)]; }
    else                   { j = i-OFF_DW2T; v = dW2[(j%12)*512  + (j/12)];  }
    ws[i] = v;
  }
}

// one 512-wide dense layer: out[r][h] = relu(bias[h] + sum_k in[r][k]*WT[k][h])
// thread tile: 4 rows x 8 cols. WT is [K][512] (coalesced float4); in-reads are
// wave-uniform LDS broadcasts. Mid-function barrier allows in==out (in-place).
template<int K, int IS>
__device__ __forceinline__ void layer512(const float (*in)[IS], const float* __restrict__ WT,
                                         const float* __restrict__ bias, float (*outlds)[HID],
                                         int rg, int h0)
{
  float acc[4][8];
  #pragma unroll
  for (int j = 0; j < 8; ++j) {
    float bb = bias[h0+j];
    #pragma unroll
    for (int i = 0; i < 4; ++i) acc[i][j] = bb;
  }
  #pragma unroll 4
  for (int k = 0; k < K; ++k) {
    const float4 wA = *reinterpret_cast<const float4*>(WT + k*HID + h0);
    const float4 wB = *reinterpret_cast<const float4*>(WT + k*HID + h0 + 4);
    #pragma unroll
    for (int i = 0; i < 4; ++i) {
      const float a = in[rg*4+i][k];
      acc[i][0] = fmaf(a, wA.x, acc[i][0]);
      acc[i][1] = fmaf(a, wA.y, acc[i][1]);
      acc[i][2] = fmaf(a, wA.z, acc[i][2]);
      acc[i][3] = fmaf(a, wA.w, acc[i][3]);
      acc[i][4] = fmaf(a, wB.x, acc[i][4]);
      acc[i][5] = fmaf(a, wB.y, acc[i][5]);
      acc[i][6] = fmaf(a, wB.z, acc[i][6]);
      acc[i][7] = fmaf(a, wB.w, acc[i][7]);
    }
  }
  __syncthreads();   // all reads of `in` complete before (possibly aliased) write
  #pragma unroll
  for (int i = 0; i < 4; ++i) {
    #pragma unroll
    for (int j = 0; j < 8; ++j) outlds[rg*4+i][h0+j] = fmaxf(acc[i][j], 0.f);
  }
}

__global__ void __launch_bounds__(256)
vae_main(const float* __restrict__ initial_c, const float* __restrict__ initial_s,
         const float* __restrict__ current_c, const float* __restrict__ eps,
         const float* __restrict__ enc_b0, const float* __restrict__ enc_b1,
         const float* __restrict__ bm, const float* __restrict__ bv,
         const float* __restrict__ dec_b0, const float* __restrict__ dec_b1,
         const float* __restrict__ dec_b2, const float* __restrict__ ws,
         float* __restrict__ out)
{
  __shared__ float s_x[TM][48];    // [one_hot 0..4 | s 5..19 | gi 20..31 | gc 32..43]
  __shared__ float s_d[TM][48];    // [one_hot 0..4 | z 5..13 | s 14..28 | gi 29..40]
  __shared__ float s_h[TM][HID];   // activations (in-place across layers)
  __shared__ float s_rec[TM][30];  // scatter accumulator

  const float* eW0T = ws + OFF_EW0T;
  const float* eW1T = ws + OFF_EW1T;
  const float* WmT  = ws + OFF_WMT;
  const float* WvT  = ws + OFF_WVT;
  const float* dW0T = ws + OFF_DW0T;
  const float* dW1T = ws + OFF_DW1T;
  const float* dW2T = ws + OFF_DW2T;

  const int t = threadIdx.x;
  const int bbase = blockIdx.x * TM;
  const int rg = t >> 6;          // row group: 4 rows each
  const int h0 = (t & 63) * 8;    // 8 output cols

  // initial_s is object-independent: load once
  for (int s = t; s < TM*15; s += 256) s_x[s/15][5 + s%15] = initial_s[(bbase + s/15)*15 + (s%15)];
  for (int s = t; s < TM*30; s += 256) s_rec[s/30][s%30] = 0.f;

  for (int o = 0; o < NOBJ; ++o) {
    __syncthreads();   // previous iteration fully done with s_x/s_h/s_rec
    for (int s = t; s < TM*5; s += 256) s_x[s/5][s%5] = (s%5 == o) ? 1.f : 0.f;
    for (int s = t; s < TM*12; s += 256) {
      const int r = s/12, j = s%12, col = d_OIDS[o][j];
      s_x[r][20+j] = initial_c[(bbase+r)*30 + col];
      s_x[r][32+j] = current_c[(bbase+r)*30 + col];
    }
    __syncthreads();

    layer512<44,48>(s_x, eW0T, enc_b0, s_h, rg, h0);     // h1
    __syncthreads();
    layer512<512,HID>(s_h, eW1T, enc_b1, s_h, rg, h0);   // h2 (in place)
    __syncthreads();

    // heads: means / log_var / z   (144 threads, K=512)
    if (t < TM*9) {
      const int r = t/9, l = t%9;
      float am = bm[l], av = bv[l];
      for (int k = 0; k < HID; ++k) {
        const float hh = s_h[r][k];
        am = fmaf(hh, WmT[k*9+l], am);
        av = fmaf(hh, WvT[k*9+l], av);
      }
      const int gid = (o*BATCH + bbase + r)*9 + l;
      out[OUT_MEANS + gid] = am;
      out[OUT_LV    + gid] = av;
      const float zz = fmaf(eps[gid], expf(0.5f*av), am);
      out[OUT_Z     + gid] = zz;
      s_d[r][5+l] = zz;
    }
    // build decoder input (non-z parts); disjoint from head writes [5..13]
    for (int s = t; s < TM*32; s += 256) {
      const int r = s/32, c = s%32;
      if (c < 5) s_d[r][c] = (c == o) ? 1.f : 0.f;
      else       s_d[r][c+9] = s_x[r][c];   // s: [14..28]<-[5..19], gi: [29..40]<-[20..31]
    }
    __syncthreads();

    layer512<41,48>(s_d, dW0T, dec_b0, s_h, rg, h0);     // g1
    __syncthreads();
    layer512<512,HID>(s_h, dW1T, dec_b1, s_h, rg, h0);   // g2 (in place)
    __syncthreads();

    // dec2 head + sigmoid + local scatter (192 threads, distinct (r,col) per o)
    if (t < TM*12) {
      const int r = t/12, j = t%12;
      float a = dec_b2[j];
      for (int k = 0; k < HID; ++k) a = fmaf(s_h[r][k], dW2T[k*12+j], a);
      const float sg = 1.f / (1.f + expf(-a));
      s_rec[r][d_OIDS[o][j]] += sg;
    }
  }

  __syncthreads();
  for (int s = t; s < TM*30; s += 256)
    out[(bbase + s/30)*30 + s%30] = s_rec[s/30][s%30];
}

// ---------------- fallback (ws too small): correct but slow ----------------
__global__ void __launch_bounds__(256)
vae_naive(const float* __restrict__ initial_c, const float* __restrict__ initial_s,
          const float* __restrict__ current_c, const float* __restrict__ eps,
          const float* eW0, const float* eb0, const float* eW1, const float* eb1,
          const float* Wm, const float* bm, const float* Wv, const float* bv,
          const float* dW0, const float* db0, const float* dW1, const float* db1,
          const float* dW2, const float* db2, float* out)
{
  __shared__ float xs[44], ds[41], h1[HID], h2[HID], rec[30];
  const int b = blockIdx.x, t = threadIdx.x;
  if (t < 30) rec[t] = 0.f;
  for (int o = 0; o < NOBJ; ++o) {
    __syncthreads();
    if (t < 44) {
      float v;
      if      (t < 5)  v = (t == o) ? 1.f : 0.f;
      else if (t < 20) v = initial_s[b*15 + (t-5)];
      else if (t < 32) v = initial_c[b*30 + d_OIDS[o][t-20]];
      else             v = current_c[b*30 + d_OIDS[o][t-32]];
      xs[t] = v;
    }
    __syncthreads();
    for (int h = t; h < HID; h += 256) {
      float a = eb0[h];
      for (int k = 0; k < 44; ++k) a = fmaf(xs[k], eW0[h*44+k], a);
      h1[h] = fmaxf(a, 0.f);
    }
    __syncthreads();
    for (int h = t; h < HID; h += 256) {
      float a = eb1[h];
      for (int k = 0; k < HID; ++k) a = fmaf(h1[k], eW1[h*512+k], a);
      h2[h] = fmaxf(a, 0.f);
    }
    __syncthreads();
    if (t < 9) {
      float am = bm[t], av = bv[t];
      for (int k = 0; k < HID; ++k) { am = fmaf(h2[k], Wm[t*512+k], am); av = fmaf(h2[k], Wv[t*512+k], av); }
      const int gid = (o*BATCH + b)*9 + t;
      out[OUT_MEANS + gid] = am;
      out[OUT_LV    + gid] = av;
      const float zz = fmaf(eps[gid], expf(0.5f*av), am);
      out[OUT_Z     + gid] = zz;
      ds[5+t] = zz;
    }
    if (t < 41 && (t < 5 || t >= 14)) {
      float v;
      if      (t < 5)  v = (t == o) ? 1.f : 0.f;
      else if (t < 29) v = initial_s[b*15 + (t-14)];
      else             v = initial_c[b*30 + d_OIDS[o][t-29]];
      ds[t] = v;
    }
    __syncthreads();
    for (int h = t; h < HID; h += 256) {
      float a = db0[h];
      for (int k = 0; k < 41; ++k) a = fmaf(ds[k], dW0[h*41+k], a);
      h1[h] = fmaxf(a, 0.f);
    }
    __syncthreads();
    for (int h = t; h < HID; h += 256) {
      float a = db1[h];
      for (int k = 0; k < HID; ++k) a = fmaf(h1[k], dW1[h*512+k], a);
      h2[h] = fmaxf(a, 0.f);
    }
    __syncthreads();
    if (t < 12) {
      float a = db2[t];
      for (int k = 0; k < HID; ++k) a = fmaf(h2[k], dW2[t*512+k], a);
      rec[d_OIDS[o][t]] += 1.f / (1.f + expf(-a));
    }
  }
  __syncthreads();
  if (t < 30) out[b*30+t] = rec[t];
}

extern "C" void kernel_launch(void* const* d_in, const int* in_sizes, int n_in,
                              void* d_out, int out_size, void* d_ws, size_t ws_size,
                              hipStream_t stream)
{
  const float* initial_c = (const float*)d_in[0];
  const float* initial_s = (const float*)d_in[1];
  const float* current_c = (const float*)d_in[2];
  const float* eps       = (const float*)d_in[3];
  const float* eW0 = (const float*)d_in[4];
  const float* eb0 = (const float*)d_in[5];
  const float* eW1 = (const float*)d_in[6];
  const float* eb1 = (const float*)d_in[7];
  const float* Wm  = (const float*)d_in[8];
  const float* bm  = (const float*)d_in[9];
  const float* Wv  = (const float*)d_in[10];
  const float* bv  = (const float*)d_in[11];
  const float* dW0 = (const float*)d_in[12];
  const float* db0 = (const float*)d_in[13];
  const float* dW1 = (const float*)d_in[14];
  const float* db1 = (const float*)d_in[15];
  const float* dW2 = (const float*)d_in[16];
  const float* db2 = (const float*)d_in[17];
  float* out = (float*)d_out;

  if (ws_size >= (size_t)WS_FLOATS * sizeof(float)) {
    float* ws = (float*)d_ws;
    prep_kernel<<<512, 256, 0, stream>>>(eW0, eW1, Wm, Wv, dW0, dW1, dW2, ws);
    vae_main<<<BATCH/TM, 256, 0, stream>>>(initial_c, initial_s, current_c, eps,
                                           eb0, eb1, bm, bv, db0, db1, db2, ws, out);
  } else {
    vae_naive<<<BATCH, 256, 0, stream>>>(initial_c, initial_s, current_c, eps,
                                         eW0, eb0, eW1, eb1, Wm, bm, Wv, bv,
                                         dW0, db0, dW1, db1, dW2, db2, out);
  }
}

// Round 2
// 1460.595 us; speedup vs baseline: 2.2808x; 2.2808x over previous
//
#include <hip/hip_runtime.h>
#include <math.h>

// ---------------- problem constants ----------------
#define BATCH 32768
#define HID   512
#define NOBJ  5
#define TM    64            // batch rows per block (MFMA path)

typedef __attribute__((ext_vector_type(8))) short bf16x8;
typedef __attribute__((ext_vector_type(4))) float f32x4;

__device__ __constant__ int d_OIDS[5][12] = {
  {0,1,2,3, 10,11,12,13,14,18,22,26},
  {0,4,5,6, 10,14,15,16,17,19,23,27},
  {1,4,7,8, 11,15,18,19,20,21,24,28},
  {2,5,7,9, 12,16,20,22,23,24,25,29},
  {3,6,8,9, 13,17,21,25,26,27,28,29}
};

// ---------------- bf16 weight workspace (ushort offsets) ----------------
#define UO_EW0   0                       // [512][64]  (K padded 44->64)
#define UO_EW1   (UO_EW0 + 512*64)       // [512][512]
#define UO_HEADS (UO_EW1 + 512*512)      // [32][512]: rows 0-8 Wm, 16-24 Wv, rest 0
#define UO_DW0   (UO_HEADS + 32*512)     // [512][64]  (K padded 41->64)
#define UO_DW1   (UO_DW0 + 512*64)       // [512][512]
#define UO_DW2   (UO_DW1 + 512*512)      // [16][512]: rows 0-11 dec_W2, rest 0
#define UO_TOTAL (UO_DW2 + 16*512)       // 614400 ushorts = 1.23 MB

// ---------------- output layout (floats) ----------------
#define OUT_MEANS (BATCH*30)
#define OUT_LV    (OUT_MEANS + NOBJ*BATCH*9)
#define OUT_Z     (OUT_LV    + NOBJ*BATCH*9)

// round-to-nearest-even f32 -> bf16 bits
__device__ __forceinline__ unsigned short f2b(float x) {
  unsigned int u = __builtin_bit_cast(unsigned int, x);
  u += 0x7FFFu + ((u >> 16) & 1u);
  return (unsigned short)(u >> 16);
}

// ---------------- prep: convert/pad/transide weights into ws (bf16) ----------------
__global__ void __launch_bounds__(256)
prep_bf16(const float* __restrict__ eW0, const float* __restrict__ eW1,
          const float* __restrict__ Wm,  const float* __restrict__ Wv,
          const float* __restrict__ dW0, const float* __restrict__ dW1,
          const float* __restrict__ dW2, unsigned short* __restrict__ ws)
{
  for (int i = blockIdx.x*blockDim.x + threadIdx.x; i < UO_TOTAL; i += gridDim.x*blockDim.x) {
    float v = 0.f; int j;
    if (i < UO_EW1) {                       // [512][64] <- eW0 [512][44]
      j = i - UO_EW0; int h = j >> 6, k = j & 63;
      if (k < 44) v = eW0[h*44 + k];
    } else if (i < UO_HEADS) {              // [512][512] <- eW1
      j = i - UO_EW1; v = eW1[j];
    } else if (i < UO_DW0) {                // [32][512] heads
      j = i - UO_HEADS; int r = j >> 9, k = j & 511;
      if (r < 9)                 v = Wm[r*512 + k];
      else if (r >= 16 && r < 25) v = Wv[(r-16)*512 + k];
    } else if (i < UO_DW1) {                // [512][64] <- dW0 [512][41]
      j = i - UO_DW0; int h = j >> 6, k = j & 63;
      if (k < 41) v = dW0[h*41 + k];
    } else if (i < UO_DW2) {                // [512][512] <- dW1
      j = i - UO_DW1; v = dW1[j];
    } else {                                // [16][512] <- dW2 [12][512]
      j = i - UO_DW2; int r = j >> 9, k = j & 511;
      if (r < 12) v = dW2[r*512 + k];
    }
    ws[i] = f2b(v);
  }
}

// One dense layer via MFMA: out[64][512] = relu(in[64][K] * W^T + bias)
// wave covers cols [wave*128, wave*128+128) (8 N-tiles) x all 64 rows (4 M-tiles).
// Wb is [512][K] bf16 (out-major, K contiguous). sIn is XOR-swizzled bf16 LDS.
// In-place (sIn==sOut) is safe: all K-loop reads complete before the mid barrier.
template<int KT, int ROWW>   // K = KT*32
__device__ __forceinline__ void layer_mfma(const unsigned short* sIn,
                                           const unsigned short* __restrict__ Wb,
                                           const float* __restrict__ bias,
                                           unsigned short* sOut,
                                           int wave, int lane)
{
  const int lcol = lane & 15;
  const int lk   = (lane >> 4) * 8;
  const int colbase = wave * 128;
  f32x4 acc[4][8];
  #pragma unroll
  for (int n = 0; n < 8; ++n) {
    const float bv = bias[colbase + n*16 + lcol];
    #pragma unroll
    for (int m = 0; m < 4; ++m) acc[m][n] = (f32x4){bv, bv, bv, bv};
  }
  for (int kt = 0; kt < KT; ++kt) {
    const int k0 = kt*32 + lk;
    bf16x8 a[4], b[8];
    #pragma unroll
    for (int m = 0; m < 4; ++m) {
      const int row = m*16 + lcol;
      a[m] = *(const bf16x8*)&sIn[row*ROWW + (k0 ^ ((row & 7) << 3))];
    }
    #pragma unroll
    for (int n = 0; n < 8; ++n)
      b[n] = *(const bf16x8*)&Wb[(colbase + n*16 + lcol)*(KT*32) + k0];
    #pragma unroll
    for (int n = 0; n < 8; ++n)
      #pragma unroll
      for (int m = 0; m < 4; ++m)
        acc[m][n] = __builtin_amdgcn_mfma_f32_16x16x32_bf16(a[m], b[n], acc[m][n], 0, 0, 0);
  }
  __syncthreads();   // all reads of sIn done before (possibly aliased) writes
  const int rbase = (lane >> 4) * 4;
  #pragma unroll
  for (int m = 0; m < 4; ++m)
    #pragma unroll
    for (int n = 0; n < 8; ++n) {
      const int col = colbase + n*16 + lcol;
      #pragma unroll
      for (int r = 0; r < 4; ++r) {
        const int row = m*16 + rbase + r;
        sOut[row*512 + (col ^ ((row & 7) << 3))] = f2b(fmaxf(acc[m][n][r], 0.f));
      }
    }
  __syncthreads();
}

__global__ void __launch_bounds__(256, 2)
vae_mfma(const float* __restrict__ initial_c, const float* __restrict__ initial_s,
         const float* __restrict__ current_c, const float* __restrict__ eps,
         const float* __restrict__ enc_b0, const float* __restrict__ enc_b1,
         const float* __restrict__ bm, const float* __restrict__ bv,
         const float* __restrict__ dec_b0, const float* __restrict__ dec_b1,
         const float* __restrict__ dec_b2, const unsigned short* __restrict__ ws,
         float* __restrict__ out)
{
  __shared__ __align__(16) unsigned short s_act[64*512];  // 64 KB activations (in-place)
  __shared__ __align__(16) unsigned short s_in[64*64];    // 8 KB enc/dec input (K padded 64)
  __shared__ float s_rec[64*30];                          // 7.5 KB scatter accumulator

  const int t = threadIdx.x;
  const int wave = t >> 6, lane = t & 63;
  const int lcol = lane & 15, lk = (lane >> 4) * 8, rbase = (lane >> 4) * 4;
  const int bbase = blockIdx.x * TM;

  for (int s = t; s < 64*30; s += 256) s_rec[s] = 0.f;

  for (int o = 0; o < NOBJ; ++o) {
    __syncthreads();

    // ---- build encoder input [64][64]: [oh 0-4 | s 5-19 | gi 20-31 | gc 32-43 | 0] ----
    for (int s = t; s < 64*64; s += 256) {
      const int row = s >> 6, col = s & 63;
      float v = 0.f;
      if (col < 5)       v = (col == o) ? 1.f : 0.f;
      else if (col < 20) v = initial_s[(bbase+row)*15 + col - 5];
      else if (col < 32) v = initial_c[(bbase+row)*30 + d_OIDS[o][col-20]];
      else if (col < 44) v = current_c[(bbase+row)*30 + d_OIDS[o][col-32]];
      s_in[row*64 + (col ^ ((row & 7) << 3))] = f2b(v);
    }
    __syncthreads();

    layer_mfma<2, 64>  (s_in,  ws + UO_EW0, enc_b0, s_act, wave, lane);  // h1
    layer_mfma<16, 512>(s_act, ws + UO_EW1, enc_b1, s_act, wave, lane);  // h2 in-place

    // ---- heads: means / log_var / z  +  build decoder input (non-z cols) ----
    {
      // decoder input: [oh 0-4 | z 5-13 | s 14-28 | gi 29-40 | 0]; z written below
      for (int s = t; s < 64*64; s += 256) {
        const int row = s >> 6, col = s & 63;
        if (col >= 5 && col < 14) continue;
        float v = 0.f;
        if (col < 5)       v = (col == o) ? 1.f : 0.f;
        else if (col < 29) v = initial_s[(bbase+row)*15 + col - 14];
        else if (col < 41) v = initial_c[(bbase+row)*30 + d_OIDS[o][col-29]];
        s_in[row*64 + (col ^ ((row & 7) << 3))] = f2b(v);
      }
      const float bmv = (lcol < 9) ? bm[lcol] : 0.f;
      const float bvv = (lcol < 9) ? bv[lcol] : 0.f;
      f32x4 am = (f32x4){bmv, bmv, bmv, bmv};
      f32x4 av = (f32x4){bvv, bvv, bvv, bvv};
      const unsigned short* hw = ws + UO_HEADS;
      for (int kt = 0; kt < 16; ++kt) {
        const int k0 = kt*32 + lk;
        const int row = wave*16 + lcol;
        bf16x8 a  = *(const bf16x8*)&s_act[row*512 + (k0 ^ ((row & 7) << 3))];
        bf16x8 bM = *(const bf16x8*)&hw[lcol*512 + k0];
        bf16x8 bV = *(const bf16x8*)&hw[(16 + lcol)*512 + k0];
        am = __builtin_amdgcn_mfma_f32_16x16x32_bf16(a, bM, am, 0, 0, 0);
        av = __builtin_amdgcn_mfma_f32_16x16x32_bf16(a, bV, av, 0, 0, 0);
      }
      if (lcol < 9) {
        #pragma unroll
        for (int r = 0; r < 4; ++r) {
          const int row = wave*16 + rbase + r;
          const int gid = (o*BATCH + bbase + row)*9 + lcol;
          const float m_ = am[r], v_ = av[r];
          out[OUT_MEANS + gid] = m_;
          out[OUT_LV    + gid] = v_;
          const float zz = fmaf(eps[gid], expf(0.5f*v_), m_);
          out[OUT_Z     + gid] = zz;
          s_in[row*64 + ((5 + lcol) ^ ((row & 7) << 3))] = f2b(zz);
        }
      }
    }
    __syncthreads();

    layer_mfma<2, 64>  (s_in,  ws + UO_DW0, dec_b0, s_act, wave, lane);  // g1
    layer_mfma<16, 512>(s_act, ws + UO_DW1, dec_b1, s_act, wave, lane);  // g2 in-place

    // ---- dec head: sigmoid + scatter into s_rec ----
    {
      const float b2 = (lcol < 12) ? dec_b2[lcol] : 0.f;
      f32x4 acc = (f32x4){b2, b2, b2, b2};
      const unsigned short* w2 = ws + UO_DW2;
      for (int kt = 0; kt < 16; ++kt) {
        const int k0 = kt*32 + lk;
        const int row = wave*16 + lcol;
        bf16x8 a = *(const bf16x8*)&s_act[row*512 + (k0 ^ ((row & 7) << 3))];
        bf16x8 b = *(const bf16x8*)&w2[lcol*512 + k0];
        acc = __builtin_amdgcn_mfma_f32_16x16x32_bf16(a, b, acc, 0, 0, 0);
      }
      if (lcol < 12) {
        const int c30 = d_OIDS[o][lcol];
        #pragma unroll
        for (int r = 0; r < 4; ++r) {
          const int row = wave*16 + rbase + r;
          s_rec[row*30 + c30] += 1.f / (1.f + expf(-acc[r]));
        }
      }
    }
  }

  __syncthreads();
  for (int s = t; s < 64*30; s += 256)
    out[(bbase + s/30)*30 + s%30] = s_rec[s];
}

// ---------------- fallback (ws too small): correct but slow fp32 ----------------
__global__ void __launch_bounds__(256)
vae_naive(const float* __restrict__ initial_c, const float* __restrict__ initial_s,
          const float* __restrict__ current_c, const float* __restrict__ eps,
          const float* eW0, const float* eb0, const float* eW1, const float* eb1,
          const float* Wm, const float* bm, const float* Wv, const float* bv,
          const float* dW0, const float* db0, const float* dW1, const float* db1,
          const float* dW2, const float* db2, float* out)
{
  __shared__ float xs[44], ds[41], h1[HID], h2[HID], rec[30];
  const int b = blockIdx.x, t = threadIdx.x;
  if (t < 30) rec[t] = 0.f;
  for (int o = 0; o < NOBJ; ++o) {
    __syncthreads();
    if (t < 44) {
      float v;
      if      (t < 5)  v = (t == o) ? 1.f : 0.f;
      else if (t < 20) v = initial_s[b*15 + (t-5)];
      else if (t < 32) v = initial_c[b*30 + d_OIDS[o][t-20]];
      else             v = current_c[b*30 + d_OIDS[o][t-32]];
      xs[t] = v;
    }
    __syncthreads();
    for (int h = t; h < HID; h += 256) {
      float a = eb0[h];
      for (int k = 0; k < 44; ++k) a = fmaf(xs[k], eW0[h*44+k], a);
      h1[h] = fmaxf(a, 0.f);
    }
    __syncthreads();
    for (int h = t; h < HID; h += 256) {
      float a = eb1[h];
      for (int k = 0; k < HID; ++k) a = fmaf(h1[k], eW1[h*512+k], a);
      h2[h] = fmaxf(a, 0.f);
    }
    __syncthreads();
    if (t < 9) {
      float am = bm[t], av = bv[t];
      for (int k = 0; k < HID; ++k) { am = fmaf(h2[k], Wm[t*512+k], am); av = fmaf(h2[k], Wv[t*512+k], av); }
      const int gid = (o*BATCH + b)*9 + t;
      out[OUT_MEANS + gid] = am;
      out[OUT_LV    + gid] = av;
      const float zz = fmaf(eps[gid], expf(0.5f*av), am);
      out[OUT_Z     + gid] = zz;
      ds[5+t] = zz;
    }
    if (t < 41 && (t < 5 || t >= 14)) {
      float v;
      if      (t < 5)  v = (t == o) ? 1.f : 0.f;
      else if (t < 29) v = initial_s[b*15 + (t-14)];
      else             v = initial_c[b*30 + d_OIDS[o][t-29]];
      ds[t] = v;
    }
    __syncthreads();
    for (int h = t; h < HID; h += 256) {
      float a = db0[h];
      for (int k = 0; k < 41; ++k) a = fmaf(ds[k], dW0[h*41+k], a);
      h1[h] = fmaxf(a, 0.f);
    }
    __syncthreads();
    for (int h = t; h < HID; h += 256) {
      float a = db1[h];
      for (int k = 0; k < HID; ++k) a = fmaf(h1[k], dW1[h*512+k], a);
      h2[h] = fmaxf(a, 0.f);
    }
    __syncthreads();
    if (t < 12) {
      float a = db2[t];
      for (int k = 0; k < HID; ++k) a = fmaf(h2[k], dW2[t*512+k], a);
      rec[d_OIDS[o][t]] += 1.f / (1.f + expf(-a));
    }
  }
  __syncthreads();
  if (t < 30) out[b*30+t] = rec[t];
}

extern "C" void kernel_launch(void* const* d_in, const int* in_sizes, int n_in,
                              void* d_out, int out_size, void* d_ws, size_t ws_size,
                              hipStream_t stream)
{
  const float* initial_c = (const float*)d_in[0];
  const float* initial_s = (const float*)d_in[1];
  const float* current_c = (const float*)d_in[2];
  const float* eps       = (const float*)d_in[3];
  const float* eW0 = (const float*)d_in[4];
  const float* eb0 = (const float*)d_in[5];
  const float* eW1 = (const float*)d_in[6];
  const float* eb1 = (const float*)d_in[7];
  const float* Wm  = (const float*)d_in[8];
  const float* bm  = (const float*)d_in[9];
  const float* Wv  = (const float*)d_in[10];
  const float* bv  = (const float*)d_in[11];
  const float* dW0 = (const float*)d_in[12];
  const float* db0 = (const float*)d_in[13];
  const float* dW1 = (const float*)d_in[14];
  const float* db1 = (const float*)d_in[15];
  const float* dW2 = (const float*)d_in[16];
  const float* db2 = (const float*)d_in[17];
  float* out = (float*)d_out;

  if (ws_size >= (size_t)UO_TOTAL * sizeof(unsigned short)) {
    unsigned short* ws = (unsigned short*)d_ws;
    prep_bf16<<<1024, 256, 0, stream>>>(eW0, eW1, Wm, Wv, dW0, dW1, dW2, ws);
    vae_mfma<<<BATCH/TM, 256, 0, stream>>>(initial_c, initial_s, current_c, eps,
                                           eb0, eb1, bm, bv, db0, db1, db2, ws, out);
  } else {
    vae_naive<<<BATCH, 256, 0, stream>>>(initial_c, initial_s, current_c, eps,
                                         eW0, eb0, eW1, eb1, Wm, bm, Wv, bv,
                                         dW0, db0, dW1, db1, dW2, db2, out);
  }
}